// Round 1
// baseline (349.421 us; speedup 1.0000x reference)
//
#include <hip/hip_runtime.h>
#include <math.h>

// ---------------------------------------------------------------------------
// JAX Threefry-2x32 (constexpr-capable, used both for compile-time key
// derivation and per-element device hashing).
// ---------------------------------------------------------------------------
struct K2 { unsigned a, b; };

__host__ __device__ constexpr unsigned rotl32c(unsigned x, int r) {
  return (x << r) | (x >> (32 - r));
}

__host__ __device__ constexpr K2 threefry2x32(unsigned k0, unsigned k1,
                                              unsigned x0, unsigned x1) {
  const unsigned ks2 = k0 ^ k1 ^ 0x1BD11BDAu;
  const unsigned ks[3] = {k0, k1, ks2};
  const int rotA[4] = {13, 15, 26, 6};
  const int rotB[4] = {17, 29, 16, 24};
  x0 += k0; x1 += k1;
  for (int g = 0; g < 5; ++g) {
    const int* rr = (g & 1) ? rotB : rotA;
    for (int i = 0; i < 4; ++i) {
      x0 += x1;
      x1 = rotl32c(x1, rr[i]);
      x1 ^= x0;
    }
    x0 += ks[(g + 1) % 3];
    x1 += ks[(g + 2) % 3] + (unsigned)(g + 1);
  }
  return K2{x0, x1};
}

// key(42) -> (0,42). fold_in(key,k) = threefry(key,(0,k)).
// partitionable (foldlike) split: keys[i] = threefry(folded,(0,i)).
// randint(span=128) uses only lower-bits stream from k2 = keys[1].
__host__ __device__ constexpr K2 hop_key(unsigned k) {
  K2 f = threefry2x32(0u, 42u, 0u, k);
  return threefry2x32(f.a, f.b, 0u, 1u);
}

constexpr K2 HK0 = hop_key(0u);  // hop 0 lower-bits key
constexpr K2 HK1 = hop_key(1u);  // hop 1 lower-bits key

// ---------------------------------------------------------------------------
// Sampling: out[i] = adj[ids[i/NS]*128 + ((w0^w1)&127)],
// (w0,w1) = threefry(k2, (0, i))   [partitionable random bits, 32-bit]
// ---------------------------------------------------------------------------
template <int NS>
__global__ __launch_bounds__(256) void sample_kernel(
    const int* __restrict__ ids, const int* __restrict__ adj,
    int* __restrict__ out, int n, unsigned ka, unsigned kb) {
  int i = blockIdx.x * 256 + threadIdx.x;
  if (i >= n) return;
  K2 r = threefry2x32(ka, kb, 0u, (unsigned)i);
  int col = (int)((r.a ^ r.b) & 127u);
  int m = i / NS;
  out[i] = adj[(long long)ids[m] * 128 + col];
}

// ---------------------------------------------------------------------------
// Row-gather mean: dst[m][d] = (1/S) * sum_s src[idx ? idx[m*S+s] : m*S+s][d]
// One block (256 threads) per output row; fully coalesced 1KB row reads.
// ---------------------------------------------------------------------------
__global__ __launch_bounds__(256) void mean_rows(
    const float* __restrict__ src, const int* __restrict__ idx,
    float* __restrict__ dst, int S, float invS) {
  const int m = blockIdx.x;
  const int d = threadIdx.x;
  const long long base = (long long)m * S;
  float acc = 0.f;
  for (int s = 0; s < S; ++s) {
    long long r = idx ? (long long)idx[base + s] : (base + s);
    acc += src[r * 256 + d];
  }
  dst[(long long)m * 256 + d] = acc * invS;
}

// ---------------------------------------------------------------------------
// Gather-A GEMM + ReLU:  C[m, ccol0 + bcol + n] = relu(A[row(m)] @ B[:, bcol+n])
// A: [*,256] fp32 (row index = aidx ? aidx[m] : m), B: [256,128] row-major.
// 64x64 tile, 256 threads, 4x4 micro-tile, BK=16.
// ---------------------------------------------------------------------------
__global__ __launch_bounds__(256) void gemm_relu(
    const float* __restrict__ A, const int* __restrict__ aidx,
    const float* __restrict__ B, float* __restrict__ C, int ccol0) {
  __shared__ float As[16][68];  // transposed A tile, padded
  __shared__ float Bs[16][68];

  const int t = threadIdx.x;
  const int tx = t & 15, ty = t >> 4;
  const int brow = blockIdx.x * 64;
  const int bcol = blockIdx.y * 64;

  // A tile load mapping: row = t/4 (0..63), k-seg = (t%4)*4 -> one float4
  const int arow = t >> 2;
  const int ak4 = (t & 3) << 2;
  const int grow = brow + arow;
  const long long asrc = aidx ? (long long)aidx[grow] : (long long)grow;
  const float* Ap = A + asrc * 256 + ak4;

  // B tile load mapping: kk = t/16 (0..15), n4 = (t%16)*4 -> one float4
  const int bkk = t >> 4;
  const int bn4 = (t & 15) << 2;
  const float* Bp = B + bkk * 128 + bcol + bn4;

  float acc[4][4] = {{0.f}};

  for (int k0 = 0; k0 < 256; k0 += 16) {
    float4 av = *(const float4*)(Ap + k0);
    float4 bv = *(const float4*)(Bp + (long long)k0 * 128);
    __syncthreads();  // protect LDS from previous iteration's readers
    As[ak4 + 0][arow] = av.x;
    As[ak4 + 1][arow] = av.y;
    As[ak4 + 2][arow] = av.z;
    As[ak4 + 3][arow] = av.w;
    Bs[bkk][bn4 + 0] = bv.x;
    Bs[bkk][bn4 + 1] = bv.y;
    Bs[bkk][bn4 + 2] = bv.z;
    Bs[bkk][bn4 + 3] = bv.w;
    __syncthreads();
#pragma unroll
    for (int kk = 0; kk < 16; ++kk) {
      float a0 = As[kk][(ty << 2) + 0];
      float a1 = As[kk][(ty << 2) + 1];
      float a2 = As[kk][(ty << 2) + 2];
      float a3 = As[kk][(ty << 2) + 3];
      float b0 = Bs[kk][(tx << 2) + 0];
      float b1 = Bs[kk][(tx << 2) + 1];
      float b2 = Bs[kk][(tx << 2) + 2];
      float b3 = Bs[kk][(tx << 2) + 3];
      acc[0][0] += a0 * b0; acc[0][1] += a0 * b1; acc[0][2] += a0 * b2; acc[0][3] += a0 * b3;
      acc[1][0] += a1 * b0; acc[1][1] += a1 * b1; acc[1][2] += a1 * b2; acc[1][3] += a1 * b3;
      acc[2][0] += a2 * b0; acc[2][1] += a2 * b1; acc[2][2] += a2 * b2; acc[2][3] += a2 * b3;
      acc[3][0] += a3 * b0; acc[3][1] += a3 * b1; acc[3][2] += a3 * b2; acc[3][3] += a3 * b3;
    }
  }

#pragma unroll
  for (int i = 0; i < 4; ++i) {
    const int r = brow + (ty << 2) + i;
    float* Cp = C + (long long)r * 256 + ccol0 + bcol + (tx << 2);
#pragma unroll
    for (int j = 0; j < 4; ++j) {
      float v = acc[i][j];
      Cp[j] = v > 0.f ? v : 0.f;
    }
  }
}

// ---------------------------------------------------------------------------
// Final: out[m] = (h[m] . w_out) / sqrt(max(|h[m]|^2, 1e-12)) + b_out
// ---------------------------------------------------------------------------
__global__ __launch_bounds__(256) void final_kernel(
    const float* __restrict__ h, const float* __restrict__ w,
    const float* __restrict__ b, float* __restrict__ out) {
  const int m = blockIdx.x;
  const int t = threadIdx.x;
  float v = h[(long long)m * 256 + t];
  float wv = w[t];
  float ss = v * v;
  float dd = v * wv;
  for (int off = 32; off; off >>= 1) {
    ss += __shfl_down(ss, off, 64);
    dd += __shfl_down(dd, off, 64);
  }
  __shared__ float s1[4], s2[4];
  const int wid = t >> 6, lane = t & 63;
  if (lane == 0) { s1[wid] = ss; s2[wid] = dd; }
  __syncthreads();
  if (t == 0) {
    float S = s1[0] + s1[1] + s1[2] + s1[3];
    float D = s2[0] + s2[1] + s2[2] + s2[3];
    float n = sqrtf(fmaxf(S, 1e-12f));
    out[m] = D / n + b[0];
  }
}

// ---------------------------------------------------------------------------
extern "C" void kernel_launch(void* const* d_in, const int* in_sizes, int n_in,
                              void* d_out, int out_size, void* d_ws, size_t ws_size,
                              hipStream_t stream) {
  (void)in_sizes; (void)n_in; (void)out_size; (void)ws_size;

  const float* features  = (const float*)d_in[0];  // [100000,256]
  const float* w_self_0  = (const float*)d_in[1];  // [256,128]
  const float* w_neigh_0 = (const float*)d_in[2];  // [256,128]
  const float* w_self_1  = (const float*)d_in[3];  // [256,128]
  const float* w_neigh_1 = (const float*)d_in[4];  // [256,128]
  const float* w_out     = (const float*)d_in[5];  // [256,1]
  const float* b_out     = (const float*)d_in[6];  // [1]
  const int*   node_ids  = (const int*)d_in[7];    // [1024]
  const int*   adj       = (const int*)d_in[8];    // [100000,128]
  float* out = (float*)d_out;                      // [1024]

  char* ws = (char*)d_ws;
  size_t off = 0;
  auto alloc = [&](size_t bytes) -> void* {
    void* p = ws + off;
    off = (off + bytes + 255) & ~(size_t)255;
    return p;
  };
  int*   s1   = (int*)alloc(10240 * sizeof(int));          // samples[1]
  int*   s2   = (int*)alloc(256000 * sizeof(int));         // samples[2]
  float* nm1  = (float*)alloc((size_t)10240 * 256 * 4);    // mean feats of hop-2 nbrs
  float* nm0  = (float*)alloc((size_t)1024 * 256 * 4);     // mean feats of hop-1 nbrs
  float* out1 = (float*)alloc((size_t)10240 * 256 * 4);    // layer-0 hop-1 hidden
  float* out0 = (float*)alloc((size_t)1024 * 256 * 4);     // layer-0 hop-0 hidden
  float* nml1 = (float*)alloc((size_t)1024 * 256 * 4);     // layer-1 neighbor mean
  float* hbuf = (float*)alloc((size_t)1024 * 256 * 4);     // layer-1 output

  // 1) neighbor sampling (must match JAX threefry bit-exactly)
  sample_kernel<10><<<40, 256, 0, stream>>>(node_ids, adj, s1, 10240, HK0.a, HK0.b);
  sample_kernel<25><<<1000, 256, 0, stream>>>(s1, adj, s2, 256000, HK1.a, HK1.b);

  // 2) gather means
  mean_rows<<<10240, 256, 0, stream>>>(features, s2, nm1, 25, 1.f / 25.f);
  mean_rows<<<1024, 256, 0, stream>>>(features, s1, nm0, 10, 0.1f);

  // 3) layer 0
  gemm_relu<<<dim3(160, 2), 256, 0, stream>>>(features, s1, w_self_0, out1, 0);
  gemm_relu<<<dim3(160, 2), 256, 0, stream>>>(nm1, nullptr, w_neigh_0, out1, 128);
  gemm_relu<<<dim3(16, 2), 256, 0, stream>>>(features, node_ids, w_self_0, out0, 0);
  gemm_relu<<<dim3(16, 2), 256, 0, stream>>>(nm0, nullptr, w_neigh_0, out0, 128);

  // 4) layer 1
  mean_rows<<<1024, 256, 0, stream>>>(out1, nullptr, nml1, 10, 0.1f);
  gemm_relu<<<dim3(16, 2), 256, 0, stream>>>(out0, nullptr, w_self_1, hbuf, 0);
  gemm_relu<<<dim3(16, 2), 256, 0, stream>>>(nml1, nullptr, w_neigh_1, hbuf, 128);

  // 5) l2-normalize + Dense(1)
  final_kernel<<<1024, 256, 0, stream>>>(hbuf, w_out, b_out, out);
}

// Round 2
// 254.467 us; speedup vs baseline: 1.3731x; 1.3731x over previous
//
#include <hip/hip_runtime.h>
#include <math.h>

// ---------------------------------------------------------------------------
// JAX Threefry-2x32 (constexpr for key derivation, device for per-elem hash).
// ---------------------------------------------------------------------------
struct K2 { unsigned a, b; };

__host__ __device__ constexpr unsigned rotl32c(unsigned x, int r) {
  return (x << r) | (x >> (32 - r));
}

__host__ __device__ constexpr K2 threefry2x32(unsigned k0, unsigned k1,
                                              unsigned x0, unsigned x1) {
  const unsigned ks2 = k0 ^ k1 ^ 0x1BD11BDAu;
  const unsigned ks[3] = {k0, k1, ks2};
  const int rotA[4] = {13, 15, 26, 6};
  const int rotB[4] = {17, 29, 16, 24};
  x0 += k0; x1 += k1;
  for (int g = 0; g < 5; ++g) {
    const int* rr = (g & 1) ? rotB : rotA;
    for (int i = 0; i < 4; ++i) {
      x0 += x1;
      x1 = rotl32c(x1, rr[i]);
      x1 ^= x0;
    }
    x0 += ks[(g + 1) % 3];
    x1 += ks[(g + 2) % 3] + (unsigned)(g + 1);
  }
  return K2{x0, x1};
}

// key(42)->(0,42); fold_in(key,k)=threefry(key,(0,k)); partitionable split
// keys[i]=threefry(folded,(0,i)); randint(span=128) uses lower-bits key k2.
__host__ __device__ constexpr K2 hop_key(unsigned k) {
  K2 f = threefry2x32(0u, 42u, 0u, k);
  return threefry2x32(f.a, f.b, 0u, 1u);
}

constexpr K2 HK0 = hop_key(0u);
constexpr K2 HK1 = hop_key(1u);

// ---------------------------------------------------------------------------
// Hop-1 sampling: s1[i] = adj[node_ids[i/10]*128 + ((w0^w1)&127)]
// ---------------------------------------------------------------------------
__global__ __launch_bounds__(256) void sample_hop1(
    const int* __restrict__ ids, const int* __restrict__ adj,
    int* __restrict__ out, int n) {
  int i = blockIdx.x * 256 + threadIdx.x;
  if (i >= n) return;
  K2 r = threefry2x32(HK0.a, HK0.b, 0u, (unsigned)i);
  int col = (int)((r.a ^ r.b) & 127u);
  out[i] = adj[(long long)ids[i / 10] * 128 + col];
}

// ---------------------------------------------------------------------------
// Fused hop-2 sample + gather-mean.
// One wave (64 lanes, float4 each = 1KB row) per output row m (10240 rows).
// Lanes 0..24 compute the 25 threefry samples + adj gathers in parallel;
// __shfl broadcasts row indices; 5-deep load batches hide latency.
// dst[m][:] = mean_{s<25} features[ adj[s1[m]][rand_col(m*25+s)] ][:]
// ---------------------------------------------------------------------------
__global__ __launch_bounds__(256) void sample_mean_hop2(
    const int* __restrict__ s1, const int* __restrict__ adj,
    const float* __restrict__ feat, float* __restrict__ dst) {
  const int m = blockIdx.x * 4 + (threadIdx.x >> 6);
  const int lane = threadIdx.x & 63;

  const int nid = s1[m];  // wave-uniform
  // parallel sampling in lanes 0..24
  int srow;
  {
    unsigned i = (unsigned)(m * 25 + (lane < 25 ? lane : 0));
    K2 r = threefry2x32(HK1.a, HK1.b, 0u, i);
    int col = (int)((r.a ^ r.b) & 127u);
    srow = adj[(long long)nid * 128 + col];
  }

  float4 acc = make_float4(0.f, 0.f, 0.f, 0.f);
#pragma unroll
  for (int c = 0; c < 25; c += 5) {
    float4 v[5];
#pragma unroll
    for (int j = 0; j < 5; ++j) {
      long long row = (long long)__shfl(srow, c + j, 64);
      v[j] = *(const float4*)(feat + row * 256 + (lane << 2));
    }
#pragma unroll
    for (int j = 0; j < 5; ++j) {
      acc.x += v[j].x; acc.y += v[j].y; acc.z += v[j].z; acc.w += v[j].w;
    }
  }
  const float invS = 1.f / 25.f;
  acc.x *= invS; acc.y *= invS; acc.z *= invS; acc.w *= invS;
  *(float4*)(dst + (long long)m * 256 + (lane << 2)) = acc;
}

// ---------------------------------------------------------------------------
// Generic wave-per-row mean of S rows (gathered via idx, or contiguous).
// ---------------------------------------------------------------------------
template <int S>
__global__ __launch_bounds__(256) void mean_rows_w(
    const float* __restrict__ src, const int* __restrict__ idx,
    float* __restrict__ dst, float invS) {
  const int m = blockIdx.x * 4 + (threadIdx.x >> 6);
  const int lane = threadIdx.x & 63;
  const long long base = (long long)m * S;

  int srow = 0;
  if (idx) srow = idx[base + (lane < S ? lane : 0)];

  float4 acc = make_float4(0.f, 0.f, 0.f, 0.f);
#pragma unroll
  for (int c = 0; c < S; c += 5) {
    float4 v[5];
#pragma unroll
    for (int j = 0; j < 5; ++j) {
      if (c + j < S) {
        long long row = idx ? (long long)__shfl(srow, c + j, 64) : (base + c + j);
        v[j] = *(const float4*)(src + row * 256 + (lane << 2));
      }
    }
#pragma unroll
    for (int j = 0; j < 5; ++j) {
      if (c + j < S) {
        acc.x += v[j].x; acc.y += v[j].y; acc.z += v[j].z; acc.w += v[j].w;
      }
    }
  }
  acc.x *= invS; acc.y *= invS; acc.z *= invS; acc.w *= invS;
  *(float4*)(dst + (long long)m * 256 + (lane << 2)) = acc;
}

// ---------------------------------------------------------------------------
// Multi-config gather-A GEMM + ReLU. Config selected by blockIdx.z.
// C[m, ccol0 + bcol + n] = relu(A[row(m)] @ B[:, bcol+n]); A [*,256], B [256,128].
// 64x64 tile, 256 threads, 4x4 micro-tile, BK=16, float4 LDS fragments.
// ---------------------------------------------------------------------------
struct GemmCfg {
  const float* A; const int* idx; const float* B; float* C;
  int ccol0; int mtiles;
};
struct GemmCfg4 { GemmCfg c[4]; };

__global__ __launch_bounds__(256) void gemm_relu_multi(GemmCfg4 cfgs) {
  const GemmCfg cfg = cfgs.c[blockIdx.z];
  if ((int)blockIdx.x >= cfg.mtiles) return;

  __shared__ __align__(16) float As[16][68];  // transposed A tile, padded
  __shared__ __align__(16) float Bs[16][68];

  const int t = threadIdx.x;
  const int tx = t & 15, ty = t >> 4;
  const int brow = blockIdx.x * 64;
  const int bcol = blockIdx.y * 64;

  const int arow = t >> 2;
  const int ak4 = (t & 3) << 2;
  const int grow = brow + arow;
  const long long asrc = cfg.idx ? (long long)cfg.idx[grow] : (long long)grow;
  const float* Ap = cfg.A + asrc * 256 + ak4;
  const float* Bp = cfg.B + (t >> 4) * 128 + bcol + ((t & 15) << 2);
  const int bkk = t >> 4;
  const int bn4 = (t & 15) << 2;

  float acc[4][4] = {{0.f}};

  for (int k0 = 0; k0 < 256; k0 += 16) {
    float4 av = *(const float4*)(Ap + k0);
    float4 bv = *(const float4*)(Bp + (long long)k0 * 128);
    __syncthreads();
    As[ak4 + 0][arow] = av.x;
    As[ak4 + 1][arow] = av.y;
    As[ak4 + 2][arow] = av.z;
    As[ak4 + 3][arow] = av.w;
    Bs[bkk][bn4 + 0] = bv.x;
    Bs[bkk][bn4 + 1] = bv.y;
    Bs[bkk][bn4 + 2] = bv.z;
    Bs[bkk][bn4 + 3] = bv.w;
    __syncthreads();
#pragma unroll
    for (int kk = 0; kk < 16; ++kk) {
      float4 a = *(const float4*)&As[kk][ty << 2];
      float4 b = *(const float4*)&Bs[kk][tx << 2];
      acc[0][0] += a.x * b.x; acc[0][1] += a.x * b.y; acc[0][2] += a.x * b.z; acc[0][3] += a.x * b.w;
      acc[1][0] += a.y * b.x; acc[1][1] += a.y * b.y; acc[1][2] += a.y * b.z; acc[1][3] += a.y * b.w;
      acc[2][0] += a.z * b.x; acc[2][1] += a.z * b.y; acc[2][2] += a.z * b.z; acc[2][3] += a.z * b.w;
      acc[3][0] += a.w * b.x; acc[3][1] += a.w * b.y; acc[3][2] += a.w * b.z; acc[3][3] += a.w * b.w;
    }
  }

#pragma unroll
  for (int i = 0; i < 4; ++i) {
    const int r = brow + (ty << 2) + i;
    float* Cp = cfg.C + (long long)r * 256 + cfg.ccol0 + bcol + (tx << 2);
#pragma unroll
    for (int j = 0; j < 4; ++j) {
      float v = acc[i][j];
      Cp[j] = v > 0.f ? v : 0.f;
    }
  }
}

// ---------------------------------------------------------------------------
// Final: out[m] = (h[m] . w_out) / sqrt(max(|h[m]|^2, 1e-12)) + b_out
// ---------------------------------------------------------------------------
__global__ __launch_bounds__(256) void final_kernel(
    const float* __restrict__ h, const float* __restrict__ w,
    const float* __restrict__ b, float* __restrict__ out) {
  const int m = blockIdx.x;
  const int t = threadIdx.x;
  float v = h[(long long)m * 256 + t];
  float wv = w[t];
  float ss = v * v;
  float dd = v * wv;
  for (int off = 32; off; off >>= 1) {
    ss += __shfl_down(ss, off, 64);
    dd += __shfl_down(dd, off, 64);
  }
  __shared__ float s1[4], s2[4];
  const int wid = t >> 6, lane = t & 63;
  if (lane == 0) { s1[wid] = ss; s2[wid] = dd; }
  __syncthreads();
  if (t == 0) {
    float S = s1[0] + s1[1] + s1[2] + s1[3];
    float D = s2[0] + s2[1] + s2[2] + s2[3];
    float n = sqrtf(fmaxf(S, 1e-12f));
    out[m] = D / n + b[0];
  }
}

// ---------------------------------------------------------------------------
extern "C" void kernel_launch(void* const* d_in, const int* in_sizes, int n_in,
                              void* d_out, int out_size, void* d_ws, size_t ws_size,
                              hipStream_t stream) {
  (void)in_sizes; (void)n_in; (void)out_size; (void)ws_size;

  const float* features  = (const float*)d_in[0];  // [100000,256]
  const float* w_self_0  = (const float*)d_in[1];  // [256,128]
  const float* w_neigh_0 = (const float*)d_in[2];  // [256,128]
  const float* w_self_1  = (const float*)d_in[3];  // [256,128]
  const float* w_neigh_1 = (const float*)d_in[4];  // [256,128]
  const float* w_out     = (const float*)d_in[5];  // [256,1]
  const float* b_out     = (const float*)d_in[6];  // [1]
  const int*   node_ids  = (const int*)d_in[7];    // [1024]
  const int*   adj       = (const int*)d_in[8];    // [100000,128]
  float* out = (float*)d_out;                      // [1024]

  char* ws = (char*)d_ws;
  size_t off = 0;
  auto alloc = [&](size_t bytes) -> void* {
    void* p = ws + off;
    off = (off + bytes + 255) & ~(size_t)255;
    return p;
  };
  int*   s1   = (int*)alloc(10240 * sizeof(int));          // samples[1]
  float* nm1  = (float*)alloc((size_t)10240 * 256 * 4);    // mean feats of hop-2 nbrs
  float* nm0  = (float*)alloc((size_t)1024 * 256 * 4);     // mean feats of hop-1 nbrs
  float* out1 = (float*)alloc((size_t)10240 * 256 * 4);    // layer-0 hop-1 hidden
  float* out0 = (float*)alloc((size_t)1024 * 256 * 4);     // layer-0 hop-0 hidden
  float* nml1 = (float*)alloc((size_t)1024 * 256 * 4);     // layer-1 neighbor mean
  float* hbuf = (float*)alloc((size_t)1024 * 256 * 4);     // layer-1 output

  // 1) hop-1 sampling (bit-exact JAX threefry)
  sample_hop1<<<40, 256, 0, stream>>>(node_ids, adj, s1, 10240);

  // 2) fused hop-2 sample + gather-mean; hop-1 gather-mean
  sample_mean_hop2<<<2560, 256, 0, stream>>>(s1, adj, features, nm1);
  mean_rows_w<10><<<256, 256, 0, stream>>>(features, s1, nm0, 0.1f);

  // 3) layer 0: four GEMMs in one dispatch (z-routed)
  {
    GemmCfg4 cf;
    cf.c[0] = {features, s1,       w_self_0,  out1, 0,   160};
    cf.c[1] = {nm1,      nullptr,  w_neigh_0, out1, 128, 160};
    cf.c[2] = {features, node_ids, w_self_0,  out0, 0,   16};
    cf.c[3] = {nm0,      nullptr,  w_neigh_0, out0, 128, 16};
    gemm_relu_multi<<<dim3(160, 2, 4), 256, 0, stream>>>(cf);
  }

  // 4) layer 1
  mean_rows_w<10><<<256, 256, 0, stream>>>(out1, nullptr, nml1, 0.1f);
  {
    GemmCfg4 cf;
    cf.c[0] = {out0, nullptr, w_self_1,  hbuf, 0,   16};
    cf.c[1] = {nml1, nullptr, w_neigh_1, hbuf, 128, 16};
    cf.c[2] = {nullptr, nullptr, nullptr, nullptr, 0, 0};
    cf.c[3] = {nullptr, nullptr, nullptr, nullptr, 0, 0};
    gemm_relu_multi<<<dim3(16, 2, 2), 256, 0, stream>>>(cf);
  }

  // 5) l2-normalize + Dense(1)
  final_kernel<<<1024, 256, 0, stream>>>(hbuf, w_out, b_out, out);
}